// Round 1
// baseline (13695.557 us; speedup 1.0000x reference)
//
#include <hip/hip_runtime.h>
#include <hip/hip_fp16.h>

// LSTM: B=8192, S=1024, H=256.
// Strategy: 256 blocks x 32 batch rows; persistent per-block recurrence.
// h: fp16 in LDS (double-buffered), c: fp32 in registers (MFMA C-layout).
// Gates via mfma_f32_16x16x32_f16; W streamed from L2 (512 KB, L2-resident).

typedef _Float16 f16x8 __attribute__((ext_vector_type(8)));
typedef float f32x4 __attribute__((ext_vector_type(4)));

#define HPAD 264  // 256 + 8 pad: keeps 16B alignment, breaks 16-way bank aliasing

static __device__ __forceinline__ unsigned short f32_to_f16_bits(float f) {
  union { _Float16 h; unsigned short u; } cv;
  cv.h = (_Float16)f;
  return cv.u;
}

static __device__ __forceinline__ float fast_exp2(float x) {
#if __has_builtin(__builtin_amdgcn_exp2f)
  return __builtin_amdgcn_exp2f(x);
#else
  return exp2f(x);
#endif
}
static __device__ __forceinline__ float fast_rcp(float x) {
#if __has_builtin(__builtin_amdgcn_rcpf)
  return __builtin_amdgcn_rcpf(x);
#else
  return 1.0f / x;
#endif
}
static __device__ __forceinline__ float fsig(float x) {
  return fast_rcp(1.0f + fast_exp2(-1.44269504f * x));
}
static __device__ __forceinline__ float ftanh_(float x) {
  float e = fast_exp2(2.88539008f * x);
  return 1.0f - 2.0f * fast_rcp(e + 1.0f);
}

// Build fp16 W [1024 gate-rows][256 k] (k = hidden index; col 0 of each 257-wide
// row is the x weight, extracted to w0), plus fp32 w0[1024], bias[1024].
__global__ void lstm_prep(const float* __restrict__ Wf, const float* __restrict__ Wi,
                          const float* __restrict__ Wc, const float* __restrict__ Wo,
                          const float* __restrict__ bf_, const float* __restrict__ bi_,
                          const float* __restrict__ bc_, const float* __restrict__ bo_,
                          unsigned short* __restrict__ Wh, float* __restrict__ w0,
                          float* __restrict__ bias) {
  int idx = blockIdx.x * blockDim.x + threadIdx.x;
  if (idx >= 1024 * 256) return;
  int n = idx >> 8;   // gate-row 0..1023 (f,i,cs,o blocks of 256)
  int k = idx & 255;  // hidden index 0..255
  int g = n >> 8, r = n & 255;
  const float* Ws = (g == 0) ? Wf : (g == 1) ? Wi : (g == 2) ? Wc : Wo;
  Wh[(size_t)n * 256 + k] = f32_to_f16_bits(Ws[r * 257 + 1 + k]);
  if (k == 0) {
    w0[n] = Ws[r * 257];
    const float* bs = (g == 0) ? bf_ : (g == 1) ? bi_ : (g == 2) ? bc_ : bo_;
    bias[n] = bs[r];
  }
}

__global__ __launch_bounds__(512, 2) void lstm_main(
    const unsigned short* __restrict__ Wh,   // [1024][256] fp16 bits
    const float* __restrict__ w0,            // [1024] x-weights
    const float* __restrict__ bias,          // [1024]
    const float* __restrict__ x,             // [8192][1024]
    const float* __restrict__ Wout,          // [256]
    const float* __restrict__ bout,          // [1]
    float* __restrict__ out) {               // [8192]
  __shared__ __align__(16) unsigned short hbuf[2][32][HPAD];
  __shared__ float outacc[32];

  const int tid  = threadIdx.x;
  const int wave = tid >> 6;     // 0..7, owns cols [wave*32, wave*32+32) of each gate
  const int lane = tid & 63;
  const int l15  = lane & 15;
  const int quad = lane >> 4;
  const int b_base = blockIdx.x * 32;

  for (int i = tid; i < 32 * HPAD; i += 512) (&hbuf[0][0][0])[i] = 0;  // h_0 = 0
  if (tid < 32) outacc[tid] = 0.0f;

  // Per-lane loop-invariant constants: this lane's 8 gate columns n(g,hh)+l15.
  float w0v[4][2], biasv[4][2];
#pragma unroll
  for (int g = 0; g < 4; ++g)
#pragma unroll
    for (int hh = 0; hh < 2; ++hh) {
      int n = g * 256 + wave * 32 + hh * 16 + l15;
      w0v[g][hh]  = w0[n];
      biasv[g][hh] = bias[n];
    }
  float woutv[2] = { Wout[wave * 32 + l15], Wout[wave * 32 + 16 + l15] };

  const float* xp = x + (size_t)(b_base + quad * 4) * 1024;
  const unsigned short* wp = Wh + (size_t)(wave * 32 + l15) * 256 + quad * 8;

  float cst[2][2][4];    // cell state, [m][hh][r] <-> (b = m*16+quad*4+r, j = wave*32+hh*16+l15)
  float hlast[2][2][4];  // fp32 h of most recent step (for the output GEMV)
#pragma unroll
  for (int m = 0; m < 2; ++m)
#pragma unroll
    for (int hh = 0; hh < 2; ++hh)
#pragma unroll
      for (int r = 0; r < 4; ++r) { cst[m][hh][r] = 0.0f; hlast[m][hh][r] = 0.0f; }

  __syncthreads();

  int p = 0;
#pragma unroll 1
  for (int t = 0; t < 1024; ++t) {
    // x_t for this lane's 8 batch rows
    float xv[2][4];
#pragma unroll
    for (int m = 0; m < 2; ++m)
#pragma unroll
      for (int r = 0; r < 4; ++r)
        xv[m][r] = xp[(m * 16 + r) * 1024 + t];

    // acc init = x * w0 + bias  (folds the K=257th column in without extra MFMA)
    f32x4 acc[2][4][2];
#pragma unroll
    for (int m = 0; m < 2; ++m)
#pragma unroll
      for (int g = 0; g < 4; ++g)
#pragma unroll
        for (int hh = 0; hh < 2; ++hh)
#pragma unroll
          for (int r = 0; r < 4; ++r)
            acc[m][g][hh][r] = xv[m][r] * w0v[g][hh] + biasv[g][hh];

    // K-loop: gates += h @ W^T.  A = h (LDS), B = W rows (global, L2-resident).
#pragma unroll
    for (int ks = 0; ks < 8; ++ks) {
      f16x8 a0 = *reinterpret_cast<const f16x8*>(&hbuf[p][l15][ks * 32 + quad * 8]);
      f16x8 a1 = *reinterpret_cast<const f16x8*>(&hbuf[p][16 + l15][ks * 32 + quad * 8]);
#pragma unroll
      for (int g = 0; g < 4; ++g)
#pragma unroll
        for (int hh = 0; hh < 2; ++hh) {
          f16x8 bb = *reinterpret_cast<const f16x8*>(wp + g * 65536 + hh * 4096 + ks * 32);
          acc[0][g][hh] = __builtin_amdgcn_mfma_f32_16x16x32_f16(a0, bb, acc[0][g][hh], 0, 0, 0);
          acc[1][g][hh] = __builtin_amdgcn_mfma_f32_16x16x32_f16(a1, bb, acc[1][g][hh], 0, 0, 0);
        }
    }

    // Elementwise gate update; f,i,cs,o for (b,j) are in the same lane/reg.
#pragma unroll
    for (int m = 0; m < 2; ++m)
#pragma unroll
      for (int hh = 0; hh < 2; ++hh)
#pragma unroll
        for (int r = 0; r < 4; ++r) {
          float fg = acc[m][0][hh][r];
          float ig = acc[m][1][hh][r];
          float cg = acc[m][2][hh][r];
          float og = acc[m][3][hh][r];
          float cf = fsig(fg) * cst[m][hh][r] + fsig(ig) * ftanh_(cg);
          cst[m][hh][r] = cf;
          float hv = fsig(og) * ftanh_(cf);
          hlast[m][hh][r] = hv;
          hbuf[p ^ 1][m * 16 + quad * 4 + r][wave * 32 + hh * 16 + l15] = f32_to_f16_bits(hv);
        }
    __syncthreads();
    p ^= 1;
  }

  // out[b] = sum_j h[b][j] * Wout[j] + bout, using fp32 h of the final step.
  float s[2][4];
#pragma unroll
  for (int m = 0; m < 2; ++m)
#pragma unroll
    for (int r = 0; r < 4; ++r) {
      float v = hlast[m][0][r] * woutv[0] + hlast[m][1][r] * woutv[1];
#pragma unroll
      for (int mask = 1; mask < 16; mask <<= 1)
        v += __shfl_xor(v, mask, 16);  // reduce over the 16 j's per quad-group
      s[m][r] = v;
    }
  if (l15 == 0) {
#pragma unroll
    for (int m = 0; m < 2; ++m)
#pragma unroll
      for (int r = 0; r < 4; ++r)
        atomicAdd(&outacc[m * 16 + quad * 4 + r], s[m][r]);  // across 8 waves
  }
  __syncthreads();
  if (tid < 32) out[b_base + tid] = outacc[tid] + bout[0];
}

extern "C" void kernel_launch(void* const* d_in, const int* in_sizes, int n_in,
                              void* d_out, int out_size, void* d_ws, size_t ws_size,
                              hipStream_t stream) {
  const float* x    = (const float*)d_in[0];
  const float* Wf   = (const float*)d_in[1];
  const float* bf_  = (const float*)d_in[2];
  const float* Wi   = (const float*)d_in[3];
  const float* bi_  = (const float*)d_in[4];
  const float* Wc   = (const float*)d_in[5];
  const float* bc_  = (const float*)d_in[6];
  const float* Wo   = (const float*)d_in[7];
  const float* bo_  = (const float*)d_in[8];
  const float* Wout = (const float*)d_in[9];
  const float* bout = (const float*)d_in[10];

  unsigned short* Wh = (unsigned short*)d_ws;                      // 512 KB fp16 W
  float* w0   = (float*)((char*)d_ws + 1024 * 256 * 2);            // 4 KB
  float* bias = (float*)((char*)d_ws + 1024 * 256 * 2 + 1024 * 4); // 4 KB

  lstm_prep<<<1024, 256, 0, stream>>>(Wf, Wi, Wc, Wo, bf_, bi_, bc_, bo_, Wh, w0, bias);
  lstm_main<<<256, 512, 0, stream>>>(Wh, w0, bias, x, Wout, bout, (float*)d_out);
}

// Round 2
// 7082.811 us; speedup vs baseline: 1.9336x; 1.9336x over previous
//
#include <hip/hip_runtime.h>
#include <hip/hip_fp16.h>

// LSTM B=8192 S=1024 H=256 — round 2: W-stationary-in-registers.
// 256 blocks x 512 thr; groups of 2 blocks {B, B^8} share 64 batch rows.
// Each block owns j-slice of 128 (gate rows interleaved n' = j*4+g, 512 rows
// x 256 K fp16 = 128 KB = 128 VGPR/thread as MFMA A-fragments, loaded ONCE).
// Per step: group exchanges h (64x256 fp16 = 32 KB) via global double buffer
// (same-XCD L2 under both stride-8 and contiguous blockIdx->XCD maps);
// staging via global_load_lds with XOR chunk swizzle applied at the global
// STORE side so linear DMA + swizzled ds_read_b128 is bank-balanced.
// c-state fp32 in VGPRs; f,i,cs,o of one (b,j) land in one acc f32x4.

typedef _Float16 f16x8 __attribute__((ext_vector_type(8)));
typedef float f32x4 __attribute__((ext_vector_type(4)));
typedef unsigned int u32;
typedef unsigned short u16;

#define WINT_OFF  0u
#define W0B_OFF   524288u
#define FLAG_OFF  528384u          // int[256*16] (64B stride per block)
#define HEX_OFF   1048576u         // u16[2][8192][256]
#define HEX_ELEMS (8192u*256u)

static __device__ __forceinline__ float fast_exp2(float x) {
#if __has_builtin(__builtin_amdgcn_exp2f)
  return __builtin_amdgcn_exp2f(x);
#else
  return exp2f(x);
#endif
}
static __device__ __forceinline__ float fast_rcp(float x) {
#if __has_builtin(__builtin_amdgcn_rcpf)
  return __builtin_amdgcn_rcpf(x);
#else
  return 1.0f / x;
#endif
}
static __device__ __forceinline__ float fsig(float x) {
  return fast_rcp(1.0f + fast_exp2(-1.44269504f * x));
}
static __device__ __forceinline__ float ftanh_(float x) {
  float e = fast_exp2(2.88539008f * x);
  return 1.0f - 2.0f * fast_rcp(e + 1.0f);
}
static __device__ __forceinline__ u16 f16b(float f) {
  union { _Float16 h; u16 u; } cv; cv.h = (_Float16)f; return cv.u;
}
static __device__ __forceinline__ float h2f(u16 u) {
  union { u16 u; _Float16 h; } cv; cv.u = u; return (float)cv.h;
}

// Wint[n'][k], n' = j*4 + g (gates of one j adjacent); w0b packed fp16 pair.
__global__ void lstm_prep(const float* __restrict__ Wf, const float* __restrict__ Wi,
                          const float* __restrict__ Wc, const float* __restrict__ Wo,
                          const float* __restrict__ bf_, const float* __restrict__ bi_,
                          const float* __restrict__ bc_, const float* __restrict__ bo_,
                          u16* __restrict__ Wint, u32* __restrict__ w0b) {
  int np = blockIdx.x;      // 0..1023
  int k  = threadIdx.x;     // 0..255
  int g = np & 3, j = np >> 2;
  const float* Ws = (g == 0) ? Wf : (g == 1) ? Wi : (g == 2) ? Wc : Wo;
  Wint[np * 256 + k] = f16b(Ws[j * 257 + 1 + k]);
  if (k == 0) {
    const float* bs = (g == 0) ? bf_ : (g == 1) ? bi_ : (g == 2) ? bc_ : bo_;
    w0b[np] = (u32)f16b(Ws[j * 257]) | ((u32)f16b(bs[j]) << 16);
  }
}

// Zero h_ex[0] (h_0 = 0) and flags (flag_w = 0 means "h_0 published").
__global__ void lstm_zero(u32* __restrict__ hex0, u32* __restrict__ flags) {
  int idx = blockIdx.x * 256 + threadIdx.x;
  uint4 z = uint4{0, 0, 0, 0};
  if (idx < 262144) ((uint4*)hex0)[idx] = z;
  else { int f = idx - 262144; if (f < 1024) ((uint4*)flags)[f] = z; }
}

__global__ __launch_bounds__(512, 2) void lstm_main(
    const u16* __restrict__ Wint, const u32* __restrict__ w0b,
    const float* __restrict__ x, const float* __restrict__ Wout,
    const float* __restrict__ bout, float* __restrict__ out,
    u16* __restrict__ hex, int* __restrict__ flags) {

  __shared__ __align__(16) u16 stage[64 * 256];   // 32 KB; chunk-swizzled h_t
  __shared__ __align__(16) u32 lw0b[512];         // this block's packed w0/bias

  const int tid  = threadIdx.x;
  const int wv   = tid >> 6;        // 0..7
  const int lane = tid & 63;
  const int l15  = lane & 15;
  const int quad = lane >> 4;
  const int B    = blockIdx.x;
  const int mi   = (B >> 3) & 1;                  // member in group
  const int peer = B ^ 8;                         // same XCD under both maps
  const int G    = (B & 7) | ((B >> 4) << 3);     // group 0..127, rows [G*64,+64)

  // ---- one-time: W fragments into registers (A-operand layout) ----
  // lane holds W[n' = mt*16 + l15][k = kt*32 + quad*8 + 0..7], mt = wv*4+mm
  f16x8 wfrag[4][8];
#pragma unroll
  for (int mm = 0; mm < 4; ++mm)
#pragma unroll
    for (int kt = 0; kt < 8; ++kt) {
      const u16* p = Wint + ((size_t)(mi * 512 + (wv * 4 + mm) * 16 + l15) * 256
                             + kt * 32 + quad * 8);
      wfrag[mm][kt] = *(const f16x8*)p;
    }
  lw0b[tid] = w0b[mi * 512 + tid];

  float cst[4][4];                 // c state: (b = bt*16+l15, j = mt*4+quad)
#pragma unroll
  for (int mm = 0; mm < 4; ++mm)
#pragma unroll
    for (int bt = 0; bt < 4; ++bt) cst[mm][bt] = 0.0f;

  const float* xp = x + (size_t)(G * 64 + l15) * 1024;
  const u16* src0 = hex + (size_t)G * 64 * 256;
  const u16* src1 = src0 + HEX_ELEMS;
  u16* dst0 = hex + (size_t)G * 64 * 256 + mi * 128;
  u16* dst1 = dst0 + HEX_ELEMS;
  int* const myflag = flags + B * 16;
  int* const pflag  = flags + peer * 16;

  __syncthreads();

#pragma unroll 1
  for (int t = 0; t < 1024; ++t) {
    const int p = t & 1;
    // -- wait peer published h_t (subsumes buffer-reuse handshake) --
    while (__hip_atomic_load(pflag, __ATOMIC_RELAXED, __HIP_MEMORY_SCOPE_AGENT) < t) {}

    // -- stage h_t -> LDS via async DMA (linear; data pre-swizzled in global) --
    const u16* src = p ? src1 : src0;
#pragma unroll
    for (int it = 0; it < 4; ++it) {
      int idx = it * 512 + tid;
      __builtin_amdgcn_global_load_lds(
          (const __attribute__((address_space(1))) u32*)(src + idx * 8),
          (__attribute__((address_space(3))) u32*)(stage + (it * 512 + wv * 64) * 8),
          16, 0, 0);
    }

    // -- overlap: x_t loads + acc init (x*w0 + bias) --
    float xv[4];
#pragma unroll
    for (int bt = 0; bt < 4; ++bt) xv[bt] = xp[bt * 16 * 1024 + t];

    f32x4 acc[4][4];
#pragma unroll
    for (int mm = 0; mm < 4; ++mm) {
      uint4 pk = *(const uint4*)&lw0b[(wv * 4 + mm) * 16 + quad * 4];
      float w0f[4], bsf[4];
      u32 pka[4] = {pk.x, pk.y, pk.z, pk.w};
#pragma unroll
      for (int r = 0; r < 4; ++r) { w0f[r] = h2f((u16)pka[r]); bsf[r] = h2f((u16)(pka[r] >> 16)); }
#pragma unroll
      for (int bt = 0; bt < 4; ++bt)
#pragma unroll
        for (int r = 0; r < 4; ++r) acc[mm][bt][r] = xv[bt] * w0f[r] + bsf[r];
    }
    __syncthreads();   // staging DMA drained (vmcnt) + visible

    // -- K loop: gates += h @ W^T; B-frags from swizzled LDS --
#pragma unroll
    for (int kt = 0; kt < 8; ++kt) {
      f16x8 bfr[4];
#pragma unroll
      for (int bt = 0; bt < 4; ++bt) {
        int row = bt * 16 + l15;
        int c = (kt * 4 + quad) ^ (row & 7);
        bfr[bt] = *(const f16x8*)&stage[row * 256 + c * 8];
      }
#pragma unroll
      for (int mm = 0; mm < 4; ++mm)
#pragma unroll
        for (int bt = 0; bt < 4; ++bt)
          acc[mm][bt] = __builtin_amdgcn_mfma_f32_16x16x32_f16(
              wfrag[mm][kt], bfr[bt], acc[mm][bt], 0, 0, 0);
    }
    __syncthreads();   // all waves done reading stage before overlay clobber

    // -- elementwise: f,i,cs,o in one f32x4; write h to LDS slice [64][136] --
#pragma unroll
    for (int mm = 0; mm < 4; ++mm) {
      int jl = (wv * 4 + mm) * 4 + quad;
#pragma unroll
      for (int bt = 0; bt < 4; ++bt) {
        float fg = acc[mm][bt][0], ig = acc[mm][bt][1];
        float cg = acc[mm][bt][2], og = acc[mm][bt][3];
        float c_ = fsig(fg) * cst[mm][bt] + fsig(ig) * ftanh_(cg);
        cst[mm][bt] = c_;
        float hv = fsig(og) * ftanh_(c_);
        stage[(bt * 16 + l15) * 136 + jl] = f16b(hv);
      }
    }
    __syncthreads();

    // -- cooperative coalesced store of h_{t+1} slice (swizzled position) --
    u16* dst = p ? dst0 : dst1;   // write buffer (t+1)&1
#pragma unroll
    for (int it = 0; it < 2; ++it) {
      int ch = it * 512 + tid;
      int row = ch >> 4, cj = ch & 15;
      uint4 v = *(const uint4*)&stage[row * 136 + cj * 8];
      *(uint4*)(dst + row * 256 + (cj ^ (row & 7)) * 8) = v;
    }
    __syncthreads();   // drains vmcnt: all stores in L2 before flag
    if (tid == 0)
      __hip_atomic_store(myflag, t + 1, __ATOMIC_RELAXED, __HIP_MEMORY_SCOPE_AGENT);
  }

  // ---- final: out[b] = h_1024 . Wout + bout (h_1024 in buffer 0) ----
  if (mi == 0) {
    float* lwout = (float*)lw0b;             // reuse LDS (loop fully done)
    if (tid < 256) lwout[tid] = Wout[tid];
    __syncthreads();
    if (tid < 64) {
      while (__hip_atomic_load(pflag, __ATOMIC_RELAXED, __HIP_MEMORY_SCOPE_AGENT) < 1024) {}
      int b = G * 64 + tid;
      const u16* hr = hex + (size_t)b * 256;
      int r7 = tid & 7;
      float a = 0.0f;
#pragma unroll 4
      for (int chl = 0; chl < 32; ++chl) {
        f16x8 hv = *(const f16x8*)&hr[(chl ^ r7) * 8];   // unswizzle
#pragma unroll
        for (int e = 0; e < 8; ++e) a += (float)hv[e] * lwout[chl * 8 + e];
      }
      out[b] = a + bout[0];
    }
  }
}

extern "C" void kernel_launch(void* const* d_in, const int* in_sizes, int n_in,
                              void* d_out, int out_size, void* d_ws, size_t ws_size,
                              hipStream_t stream) {
  const float* x    = (const float*)d_in[0];
  const float* Wf   = (const float*)d_in[1];
  const float* bf_  = (const float*)d_in[2];
  const float* Wi   = (const float*)d_in[3];
  const float* bi_  = (const float*)d_in[4];
  const float* Wc   = (const float*)d_in[5];
  const float* bc_  = (const float*)d_in[6];
  const float* Wo   = (const float*)d_in[7];
  const float* bo_  = (const float*)d_in[8];
  const float* Wout = (const float*)d_in[9];
  const float* bout = (const float*)d_in[10];

  u16* Wint  = (u16*)((char*)d_ws + WINT_OFF);
  u32* w0b   = (u32*)((char*)d_ws + W0B_OFF);
  int* flags = (int*)((char*)d_ws + FLAG_OFF);
  u16* hex   = (u16*)((char*)d_ws + HEX_OFF);

  lstm_prep<<<1024, 256, 0, stream>>>(Wf, Wi, Wc, Wo, bf_, bi_, bc_, bo_, Wint, w0b);
  lstm_zero<<<1028, 256, 0, stream>>>((u32*)hex, (u32*)flags);
  lstm_main<<<256, 512, 0, stream>>>(Wint, w0b, x, Wout, bout, (float*)d_out, hex, flags);
}